// Round 1
// baseline (772.328 us; speedup 1.0000x reference)
//
#include <hip/hip_runtime.h>

// out[b,h,w,d] = x[b,h,w,d] + (d < 256 ? spatial_pe[h,w,d]
//                                      : pattern_pe[idx[b,h,w] % 64][d-256])
// B=256, H=W=30, D=512, NUM_PATTERNS=64, MAX_GRID=30 (slice == full table).
// fp32 in/out. Pure memory-bound elementwise add: target HBM BW ceiling.

#define NB 256
#define NH 30
#define NW 30
#define ND 512
#define NDH 256        // D/2
#define NPAT 64

__global__ __launch_bounds__(256) void pe_add_kernel(
    const float* __restrict__ x,
    const int*   __restrict__ pidx,
    const float* __restrict__ spe,   // [30*30, 256]
    const float* __restrict__ ppe,   // [64, 256]
    float* __restrict__ out)
{
    const int total4 = NB * NH * NW * (ND / 4);   // 29,491,200 float4 groups
    const float4* __restrict__ x4   = reinterpret_cast<const float4*>(x);
    const float4* __restrict__ spe4 = reinterpret_cast<const float4*>(spe); // [900][64]
    const float4* __restrict__ ppe4 = reinterpret_cast<const float4*>(ppe); // [64][64]
    float4* __restrict__ out4 = reinterpret_cast<float4*>(out);

    const int stride = gridDim.x * blockDim.x;
    for (int e = blockIdx.x * blockDim.x + threadIdx.x; e < total4; e += stride) {
        const int pos = e >> 7;     // which (b,h,w) row (128 float4s per row)
        const int dv  = e & 127;    // float4 index within the 512-wide row

        float4 xv = x4[e];
        float4 pv;
        if (dv < 64) {
            // spatial half: spe[h][w][dv*4 ..]; hw = pos % 900
            const int hw = pos % (NH * NW);
            pv = spe4[hw * 64 + dv];
        } else {
            // pattern half: all 64 lanes of the wave share `pos` -> uniform load
            const int p = pidx[pos] & (NPAT - 1);
            pv = ppe4[p * 64 + (dv - 64)];
        }
        float4 o;
        o.x = xv.x + pv.x;
        o.y = xv.y + pv.y;
        o.z = xv.z + pv.z;
        o.w = xv.w + pv.w;
        out4[e] = o;
    }
}

extern "C" void kernel_launch(void* const* d_in, const int* in_sizes, int n_in,
                              void* d_out, int out_size, void* d_ws, size_t ws_size,
                              hipStream_t stream) {
    const float* x    = (const float*)d_in[0];
    const int*   pidx = (const int*)d_in[1];
    const float* spe  = (const float*)d_in[2];
    const float* ppe  = (const float*)d_in[3];
    float* out = (float*)d_out;

    // memory-bound: ~2048-4096 blocks + grid-stride (G11)
    const int threads = 256;
    const int blocks = 4096;
    pe_add_kernel<<<blocks, threads, 0, stream>>>(x, pidx, spe, ppe, out);
}